// Round 4
// baseline (362.362 us; speedup 1.0000x reference)
//
#include <hip/hip_runtime.h>
#include <hip/hip_bf16.h>
#include <cstdint>
#include <cstddef>

#define TT 2048      // tokens (b*t)
#define DD 1024      // d
#define HH 2048      // h
#define NE 16        // experts
#define BKW 64       // K elems per stage step
#define WMAX 48      // max (expert, m-block) work items

typedef __bf16 bf16x8 __attribute__((ext_vector_type(8)));
typedef float f32x4 __attribute__((ext_vector_type(4)));

__device__ __forceinline__ unsigned short f2bf(float f) {
  union { float f; unsigned u; } v; v.f = f;
  unsigned r = (v.u + 0x7FFFu + ((v.u >> 16) & 1u)) >> 16;  // RNE
  return (unsigned short)r;
}
__device__ __forceinline__ float bf2f(unsigned short s) {
  union { unsigned u; float f; } v; v.u = ((unsigned)s) << 16;
  return v.f;
}

__device__ __forceinline__ void gl_lds16(const void* g, void* l) {
  __builtin_amdgcn_global_load_lds(
      (const __attribute__((address_space(1))) unsigned int*)g,
      (__attribute__((address_space(3))) unsigned int*)l, 16, 0, 0);
}

// Build a K-contiguous bf16 B-fragment from an un-transposed fp32 LDS tile
// [64][32] (128B rows, source-side chunk swizzle c ^= kg<<1).
__device__ __forceinline__ bf16x8 fragB(const float* t, int ks, int kg, int n) {
  const int cst = ((n >> 2) ^ (kg << 1)) & 7;
  const float* p = t + (size_t)(ks * 32 + kg * 8) * 32 + cst * 4 + (n & 3);
  bf16x8 r;
  #pragma unroll
  for (int j = 0; j < 8; ++j) r[j] = (__bf16)p[j * 32];
  return r;
}

// ---------------- x fp32 -> bf16 ----------------
__global__ __launch_bounds__(256) void k_cvt_x(const float* __restrict__ x,
                                               unsigned short* __restrict__ xbf) {
  int i = blockIdx.x * 256 + threadIdx.x;   // 8 floats per thread
  const float4* p = reinterpret_cast<const float4*>(x) + (size_t)i * 2;
  float4 a = p[0], b = p[1];
  ushort4 o0 = { f2bf(a.x), f2bf(a.y), f2bf(a.z), f2bf(a.w) };
  ushort4 o1 = { f2bf(b.x), f2bf(b.y), f2bf(b.z), f2bf(b.w) };
  reinterpret_cast<ushort4*>(xbf)[(size_t)i * 2]     = o0;
  reinterpret_cast<ushort4*>(xbf)[(size_t)i * 2 + 1] = o1;
}

// ---------------- router + top-2 + bucketing ----------------
__global__ __launch_bounds__(256) void k_router(
    const float* __restrict__ x, const float* __restrict__ rw,
    const float* __restrict__ rb, int* __restrict__ cnt,
    int* __restrict__ list_tok, int* __restrict__ rec,
    float* __restrict__ wrec) {
  const int t = blockIdx.x;
  __shared__ float xs[DD];
  __shared__ float part[256];
  __shared__ float sc[NE];
  const float* xr = x + (size_t)t * DD;
  for (int i = threadIdx.x; i < DD; i += 256) xs[i] = xr[i];
  __syncthreads();
  const int e = threadIdx.x >> 4, j = threadIdx.x & 15;
  const float* w = rw + (size_t)e * DD;
  float s = 0.f;
  for (int i = j; i < DD; i += 16) s += xs[i] * w[i];
  part[threadIdx.x] = s;
  __syncthreads();
  if (threadIdx.x < NE) {
    float v = rb[threadIdx.x];
    #pragma unroll
    for (int q = 0; q < 16; ++q) v += part[threadIdx.x * 16 + q];
    sc[threadIdx.x] = v;
  }
  __syncthreads();
  if (threadIdx.x == 0) {
    int e1 = 0; float v1 = sc[0];
    #pragma unroll
    for (int q = 1; q < NE; ++q) { if (sc[q] > v1) { v1 = sc[q]; e1 = q; } }
    int e2 = -1; float v2 = -3.4e38f;
    #pragma unroll
    for (int q = 0; q < NE; ++q) {
      if (q != e1 && sc[q] > v2) { v2 = sc[q]; e2 = q; }
    }
    float ex = expf(v2 - v1);          // <= 1
    float w1 = 1.f / (1.f + ex);
    float w2 = ex / (1.f + ex);
    int p1 = atomicAdd(&cnt[e1], 1);
    int p2 = atomicAdd(&cnt[e2], 1);
    list_tok[e1 * TT + p1] = t;
    list_tok[e2 * TT + p2] = t;
    rec[t * 4 + 0] = e1; rec[t * 4 + 1] = p1;
    rec[t * 4 + 2] = e2; rec[t * 4 + 3] = p2;
    wrec[t * 2 + 0] = w1; wrec[t * 2 + 1] = w2;
  }
}

// ---------------- work-table builder ----------------
__global__ void k_sched(const int* __restrict__ cnt, int* __restrict__ work,
                        int* __restrict__ woff) {
  if (threadIdx.x == 0) {
    int o = 0, nw = 0;
    for (int e = 0; e < NE; ++e) {
      int ce = cnt[e];
      int nmb = (ce + 127) >> 7;
      for (int mb = 0; mb < nmb; ++mb) {
        work[nw * 2 + 0] = e; work[nw * 2 + 1] = mb; ++nw;
      }
      woff[e] = o; o += ce;
    }
    for (int q = nw; q < WMAX; ++q) { work[q * 2 + 0] = -1; work[q * 2 + 1] = 0; }
  }
}

// ---------------- up GEMMs (mag,freq) + activation ----------------
// BM=128, BN=32, BK=64. A: bf16 via gl_lds (R3 path). B: fp32 un-transposed
// tiles via gl_lds w/ source chunk-swizzle; frag via 8x ds_read_b32 + cvt.
__global__ __launch_bounds__(256, 2) void k_up(
    const unsigned short* __restrict__ xbf,
    const float* __restrict__ bmag,    // [e][DD][HH] fp32
    const float* __restrict__ bfreq,   // [e][DD][HH] fp32
    const float* __restrict__ bphase,
    const int* __restrict__ cnt, const int* __restrict__ list_tok,
    const int* __restrict__ work, const int* __restrict__ woff,
    unsigned short* __restrict__ hid) {
  const int e = work[blockIdx.x * 2 + 0];
  if (e < 0) return;
  const int mt = work[blockIdx.x * 2 + 1];
  const int nt = blockIdx.y;
  const int ce = cnt[e];
  const int off = woff[e];
  __shared__ unsigned short As[2][128][BKW];   // 32 KB
  __shared__ float Bm[2][64][32];              // 16 KB
  __shared__ float Bf[2][64][32];              // 16 KB
  __shared__ int toks[128];
  const int tid = threadIdx.x;
  if (tid < 128) {
    int r = mt * 128 + tid;
    toks[tid] = list_tok[e * TT + (r < ce ? r : ce - 1)];
  }
  __syncthreads();
  const int w = tid >> 6, l = tid & 63;
  const int lhi = l >> 3, llo = l & 7;
  size_t abase[4]; int aoff[4];
  #pragma unroll
  for (int j = 0; j < 4; ++j) {
    int seg = w * 4 + j;
    int r = seg * 8 + lhi;
    abase[j] = (size_t)toks[r] * DD + (size_t)(((llo ^ (r & 7)) * 8));
    aoff[j] = seg * 512 + l * 8;
  }
  const int n0 = nt * 32;
  const float* srcM = bmag  + (size_t)e * DD * HH + n0;
  const float* srcF = bfreq + (size_t)e * DD * HH + n0;
  // B staging indices (per thread, 2 chunks per matrix per kt)
  int bk[2], bc[2], bL[2];
  #pragma unroll
  for (int s = 0; s < 2; ++s) {
    int L = s * 256 + tid;
    int k = L >> 3, cst = L & 7;
    bk[s] = k; bc[s] = cst ^ (((k >> 3) & 3) << 1); bL[s] = L;
  }
  const int wm = (w >> 1) * 64, wn = (w & 1) * 16;
  const int lr = l & 15, kg = l >> 4;
  const int nfr = wn + lr;
  const f32x4 zero = {0.f, 0.f, 0.f, 0.f};
  f32x4 accM[4], accF[4];
  #pragma unroll
  for (int a = 0; a < 4; ++a) { accM[a] = zero; accF[a] = zero; }

  auto stage = [&](int buf, int kt) {
    const int ko = kt * BKW;
    unsigned short* As_b = &As[buf][0][0];
    char* Bm_b = (char*)&Bm[buf][0][0];
    char* Bf_b = (char*)&Bf[buf][0][0];
    #pragma unroll
    for (int j = 0; j < 4; ++j) gl_lds16(xbf + abase[j] + ko, As_b + aoff[j]);
    #pragma unroll
    for (int s = 0; s < 2; ++s) {
      gl_lds16(srcM + (size_t)(ko + bk[s]) * HH + bc[s] * 4, Bm_b + bL[s] * 16);
      gl_lds16(srcF + (size_t)(ko + bk[s]) * HH + bc[s] * 4, Bf_b + bL[s] * 16);
    }
  };

  stage(0, 0);
  __syncthreads();
  int buf = 0;
  for (int kt = 0; kt < DD / BKW; ++kt) {
    if (kt + 1 < DD / BKW) stage(buf ^ 1, kt + 1);
    #pragma unroll
    for (int ks = 0; ks < 2; ++ks) {
      const int csw = ((ks * 4 + kg) ^ (lr & 7)) * 8;
      bf16x8 av[4];
      #pragma unroll
      for (int fm = 0; fm < 4; ++fm)
        av[fm] = *reinterpret_cast<const bf16x8*>(&As[buf][wm + fm * 16 + lr][0] + csw);
      bf16x8 bmv = fragB(&Bm[buf][0][0], ks, kg, nfr);
      bf16x8 bfv = fragB(&Bf[buf][0][0], ks, kg, nfr);
      #pragma unroll
      for (int fm = 0; fm < 4; ++fm) {
        accM[fm] = __builtin_amdgcn_mfma_f32_16x16x32_bf16(av[fm], bmv, accM[fm], 0, 0, 0);
        accF[fm] = __builtin_amdgcn_mfma_f32_16x16x32_bf16(av[fm], bfv, accF[fm], 0, 0, 0);
      }
    }
    __syncthreads();
    buf ^= 1;
  }
  const int ng = nt * 32 + wn + lr;
  const float ph = bphase[e * HH + ng] + 0.1f;
  #pragma unroll
  for (int fm = 0; fm < 4; ++fm) {
    #pragma unroll
    for (int jj = 0; jj < 4; ++jj) {
      int m = mt * 128 + wm + fm * 16 + kg * 4 + jj;
      if (m < ce) {
        float mv = accM[fm][jj];
        float fv = accF[fm][jj];
        float exn = __expf(-fabsf(fv));
        float sp = fmaxf(fv, 0.f) + __logf(1.f + exn);   // stable softplus
        float t2 = __expf(2.f * mv);
        float th = 1.f - 2.f / (t2 + 1.f);               // tanh
        float hv = th * __cosf(sp + ph);
        hid[(size_t)(off + m) * HH + ng] = f2bf(hv);
      }
    }
  }
}

// ---------------- down GEMM ----------------
__global__ __launch_bounds__(256, 3) void k_down(
    const unsigned short* __restrict__ hid,
    const float* __restrict__ bdown,   // [e][HH][DD] fp32
    const int* __restrict__ cnt,
    const int* __restrict__ work, const int* __restrict__ woff,
    unsigned short* __restrict__ op) {
  const int e = work[blockIdx.x * 2 + 0];
  if (e < 0) return;
  const int mt = work[blockIdx.x * 2 + 1];
  const int nt = blockIdx.y;
  const int ce = cnt[e];
  const int off = woff[e];
  __shared__ unsigned short As[2][128][BKW];   // 32 KB
  __shared__ float Bd[2][64][32];              // 16 KB
  const int tid = threadIdx.x;
  const int w = tid >> 6, l = tid & 63;
  const int lhi = l >> 3, llo = l & 7;
  size_t abase[4]; int aoff[4];
  #pragma unroll
  for (int j = 0; j < 4; ++j) {
    int seg = w * 4 + j;
    int r = seg * 8 + lhi;
    int gr = mt * 128 + r; if (gr >= ce) gr = ce - 1;
    abase[j] = (size_t)(off + gr) * HH + (size_t)(((llo ^ (r & 7)) * 8));
    aoff[j] = seg * 512 + l * 8;
  }
  const int n0 = nt * 32;
  const float* srcD = bdown + (size_t)e * HH * DD + n0;
  int bk[2], bc[2], bL[2];
  #pragma unroll
  for (int s = 0; s < 2; ++s) {
    int L = s * 256 + tid;
    int k = L >> 3, cst = L & 7;
    bk[s] = k; bc[s] = cst ^ (((k >> 3) & 3) << 1); bL[s] = L;
  }
  const int wm = (w >> 1) * 64, wn = (w & 1) * 16;
  const int lr = l & 15, kg = l >> 4;
  const int nfr = wn + lr;
  const f32x4 zero = {0.f, 0.f, 0.f, 0.f};
  f32x4 acc[4];
  #pragma unroll
  for (int a = 0; a < 4; ++a) acc[a] = zero;

  auto stage = [&](int buf, int kt) {
    const int ko = kt * BKW;
    unsigned short* As_b = &As[buf][0][0];
    char* Bd_b = (char*)&Bd[buf][0][0];
    #pragma unroll
    for (int j = 0; j < 4; ++j) gl_lds16(hid + abase[j] + ko, As_b + aoff[j]);
    #pragma unroll
    for (int s = 0; s < 2; ++s)
      gl_lds16(srcD + (size_t)(ko + bk[s]) * DD + bc[s] * 4, Bd_b + bL[s] * 16);
  };

  stage(0, 0);
  __syncthreads();
  int buf = 0;
  for (int kt = 0; kt < HH / BKW; ++kt) {
    if (kt + 1 < HH / BKW) stage(buf ^ 1, kt + 1);
    #pragma unroll
    for (int ks = 0; ks < 2; ++ks) {
      const int csw = ((ks * 4 + kg) ^ (lr & 7)) * 8;
      bf16x8 av[4];
      #pragma unroll
      for (int fm = 0; fm < 4; ++fm)
        av[fm] = *reinterpret_cast<const bf16x8*>(&As[buf][wm + fm * 16 + lr][0] + csw);
      bf16x8 bv = fragB(&Bd[buf][0][0], ks, kg, nfr);
      #pragma unroll
      for (int fm = 0; fm < 4; ++fm)
        acc[fm] = __builtin_amdgcn_mfma_f32_16x16x32_bf16(av[fm], bv, acc[fm], 0, 0, 0);
    }
    __syncthreads();
    buf ^= 1;
  }
  const int ng = nt * 32 + wn + lr;
  #pragma unroll
  for (int fm = 0; fm < 4; ++fm) {
    #pragma unroll
    for (int jj = 0; jj < 4; ++jj) {
      int m = mt * 128 + wm + fm * 16 + kg * 4 + jj;
      if (m < ce)
        op[(size_t)(off + m) * DD + ng] = f2bf(acc[fm][jj]);
    }
  }
}

// ---------------- combine + RMSNorm ----------------
__global__ __launch_bounds__(256) void k_norm(
    const unsigned short* __restrict__ op, const int* __restrict__ woff,
    const int* __restrict__ rec, const float* __restrict__ wrec,
    const float* __restrict__ nw, float* __restrict__ out) {
  const int t = blockIdx.x;
  const int tid = threadIdx.x;
  __shared__ float red[4];
  const int e1 = rec[t * 4 + 0], p1 = rec[t * 4 + 1];
  const int e2 = rec[t * 4 + 2], p2 = rec[t * 4 + 3];
  const float w1 = wrec[t * 2 + 0], w2 = wrec[t * 2 + 1];
  const unsigned short* pa = op + (size_t)(woff[e1] + p1) * DD;
  const unsigned short* pb = op + (size_t)(woff[e2] + p2) * DD;
  float v[4]; float ss = 0.f;
  #pragma unroll
  for (int q = 0; q < 4; ++q) {
    int i = q * 256 + tid;
    v[q] = w1 * bf2f(pa[i]) + w2 * bf2f(pb[i]);
    ss += v[q] * v[q];
  }
  #pragma unroll
  for (int o = 32; o > 0; o >>= 1) ss += __shfl_xor(ss, o);
  if ((tid & 63) == 0) red[tid >> 6] = ss;
  __syncthreads();
  const float tot = red[0] + red[1] + red[2] + red[3];
  const float scl = rsqrtf(tot * (1.f / DD) + 1e-6f);
  #pragma unroll
  for (int q = 0; q < 4; ++q) {
    int i = q * 256 + tid;
    out[(size_t)t * DD + i] = v[q] * scl * nw[i];
  }
}

extern "C" void kernel_launch(void* const* d_in, const int* in_sizes, int n_in,
                              void* d_out, int out_size, void* d_ws, size_t ws_size,
                              hipStream_t stream) {
  const float* x      = (const float*)d_in[0];
  const float* rw     = (const float*)d_in[1];
  const float* rb     = (const float*)d_in[2];
  const float* bmag   = (const float*)d_in[3];
  const float* bfreq  = (const float*)d_in[4];
  const float* bphase = (const float*)d_in[5];
  const float* bdown  = (const float*)d_in[6];
  const float* nw     = (const float*)d_in[7];
  float* out = (float*)d_out;
  char* ws = (char*)d_ws;
  const size_t MB = 1024 * 1024;
  int*   cnt  = (int*)(ws + 0);          // 16 int
  int*   work = (int*)(ws + 128);        // WMAX*2 int
  int*   woff = (int*)(ws + 1024);       // 16 int
  int*   list = (int*)(ws + 4096);       // 16*2048 int
  int*   rec  = (int*)(ws + 139264);     // 2048*4 int
  float* wrec = (float*)(ws + 172032);   // 2048*2 f32
  unsigned short* xbf = (unsigned short*)(ws + 1 * MB);    // 4 MB
  unsigned short* hid = (unsigned short*)(ws + 5 * MB);    // 16 MB
  unsigned short* op  = (unsigned short*)(ws + 21 * MB);   // 8 MB

  hipMemsetAsync(cnt, 0, 64, stream);
  k_cvt_x<<<1024, 256, 0, stream>>>(x, xbf);
  k_router<<<TT, 256, 0, stream>>>(x, rw, rb, cnt, list, rec, wrec);
  k_sched<<<1, 64, 0, stream>>>(cnt, work, woff);
  k_up<<<dim3(WMAX, HH / 32), 256, 0, stream>>>(xbf, bmag, bfreq, bphase, cnt, list, work, woff, hid);
  k_down<<<dim3(WMAX, DD / 32), 256, 0, stream>>>(hid, bdown, cnt, work, woff, op);
  k_norm<<<TT, 256, 0, stream>>>(op, woff, rec, wrec, nw, out);
}

// Round 5
// 331.737 us; speedup vs baseline: 1.0923x; 1.0923x over previous
//
#include <hip/hip_runtime.h>
#include <hip/hip_bf16.h>
#include <cstdint>
#include <cstddef>

#define TT 2048      // tokens (b*t)
#define DD 1024      // d
#define HH 2048      // h
#define NE 16        // experts
#define WM128 48     // max (expert, 128-row block) work items
#define WM64  80     // max (expert, 64-row block) work items

typedef __bf16 bf16x8 __attribute__((ext_vector_type(8)));
typedef float f32x4 __attribute__((ext_vector_type(4)));

__device__ __forceinline__ unsigned short f2bf(float f) {
  union { float f; unsigned u; } v; v.f = f;
  unsigned r = (v.u + 0x7FFFu + ((v.u >> 16) & 1u)) >> 16;  // RNE
  return (unsigned short)r;
}
__device__ __forceinline__ float bf2f(unsigned short s) {
  union { unsigned u; float f; } v; v.u = ((unsigned)s) << 16;
  return v.f;
}

__device__ __forceinline__ void gl_lds16(const void* g, void* l) {
  __builtin_amdgcn_global_load_lds(
      (const __attribute__((address_space(1))) unsigned int*)g,
      (__attribute__((address_space(3))) unsigned int*)l, 16, 0, 0);
}

// ---------------- x fp32 -> bf16 ----------------
__global__ __launch_bounds__(256) void k_cvt_x(const float* __restrict__ x,
                                               unsigned short* __restrict__ xbf) {
  int i = blockIdx.x * 256 + threadIdx.x;   // 8 floats per thread
  const float4* p = reinterpret_cast<const float4*>(x) + (size_t)i * 2;
  float4 a = p[0], b = p[1];
  ushort4 o0 = { f2bf(a.x), f2bf(a.y), f2bf(a.z), f2bf(a.w) };
  ushort4 o1 = { f2bf(b.x), f2bf(b.y), f2bf(b.z), f2bf(b.w) };
  reinterpret_cast<ushort4*>(xbf)[(size_t)i * 2]     = o0;
  reinterpret_cast<ushort4*>(xbf)[(size_t)i * 2 + 1] = o1;
}

// ---------------- per-expert transpose: src[R][C] fp32 -> dst[C][R] bf16 ----------------
// z selects expert (z&15) and matrix (z>>4): 0 -> (src0,dst0), 1 -> (src1,dst1)
__global__ __launch_bounds__(256) void k_trans(const float* __restrict__ src0,
                                               const float* __restrict__ src1,
                                               unsigned short* __restrict__ dst0,
                                               unsigned short* __restrict__ dst1,
                                               int R, int C) {
  __shared__ unsigned short st[64][68];
  const int e = blockIdx.z & 15;
  const int m = blockIdx.z >> 4;
  const float* src = m ? src1 : src0;
  unsigned short* dst = m ? dst1 : dst0;
  const int c0 = blockIdx.x * 64, r0 = blockIdx.y * 64;
  const float* s = src + (size_t)e * R * C;
  unsigned short* d = dst + (size_t)e * R * C;
  const int tid = threadIdx.x;
  #pragma unroll
  for (int p = 0; p < 4; ++p) {
    int r = p * 16 + (tid >> 4);
    int c = (tid & 15) * 4;
    float4 v = *reinterpret_cast<const float4*>(s + (size_t)(r0 + r) * C + c0 + c);
    ushort4 o = { f2bf(v.x), f2bf(v.y), f2bf(v.z), f2bf(v.w) };
    *reinterpret_cast<ushort4*>(&st[r][c]) = o;
  }
  __syncthreads();
  #pragma unroll
  for (int q = 0; q < 4; ++q) {
    int c = q * 16 + (tid >> 4);
    int r4 = (tid & 15) * 4;
    ushort4 o = { st[r4][c], st[r4 + 1][c], st[r4 + 2][c], st[r4 + 3][c] };
    *reinterpret_cast<ushort4*>(d + (size_t)(c0 + c) * R + r0 + r4) = o;
  }
}

// ---------------- router + top-2 + bucketing ----------------
__global__ __launch_bounds__(256) void k_router(
    const float* __restrict__ x, const float* __restrict__ rw,
    const float* __restrict__ rb, int* __restrict__ cnt,
    int* __restrict__ list_tok, int* __restrict__ rec,
    float* __restrict__ wrec) {
  const int t = blockIdx.x;
  __shared__ float xs[DD];
  __shared__ float part[256];
  __shared__ float sc[NE];
  const float* xr = x + (size_t)t * DD;
  for (int i = threadIdx.x; i < DD; i += 256) xs[i] = xr[i];
  __syncthreads();
  const int e = threadIdx.x >> 4, j = threadIdx.x & 15;
  const float* w = rw + (size_t)e * DD;
  float s = 0.f;
  for (int i = j; i < DD; i += 16) s += xs[i] * w[i];
  part[threadIdx.x] = s;
  __syncthreads();
  if (threadIdx.x < NE) {
    float v = rb[threadIdx.x];
    #pragma unroll
    for (int q = 0; q < 16; ++q) v += part[threadIdx.x * 16 + q];
    sc[threadIdx.x] = v;
  }
  __syncthreads();
  if (threadIdx.x == 0) {
    int e1 = 0; float v1 = sc[0];
    #pragma unroll
    for (int q = 1; q < NE; ++q) { if (sc[q] > v1) { v1 = sc[q]; e1 = q; } }
    int e2 = -1; float v2 = -3.4e38f;
    #pragma unroll
    for (int q = 0; q < NE; ++q) {
      if (q != e1 && sc[q] > v2) { v2 = sc[q]; e2 = q; }
    }
    float ex = expf(v2 - v1);          // <= 1
    float w1 = 1.f / (1.f + ex);
    float w2 = ex / (1.f + ex);
    int p1 = atomicAdd(&cnt[e1], 1);
    int p2 = atomicAdd(&cnt[e2], 1);
    list_tok[e1 * TT + p1] = t;
    list_tok[e2 * TT + p2] = t;
    rec[t * 4 + 0] = e1; rec[t * 4 + 1] = p1;
    rec[t * 4 + 2] = e2; rec[t * 4 + 3] = p2;
    wrec[t * 2 + 0] = w1; wrec[t * 2 + 1] = w2;
  }
}

// ---------------- work-table builder: 128-row and 64-row variants ----------------
__global__ void k_sched(const int* __restrict__ cnt, int* __restrict__ work128,
                        int* __restrict__ work64, int* __restrict__ woff) {
  if (threadIdx.x == 0) {
    int o = 0, n1 = 0, n2 = 0;
    for (int e = 0; e < NE; ++e) {
      int ce = cnt[e];
      int a = (ce + 127) >> 7;
      for (int mb = 0; mb < a; ++mb) { work128[n1 * 2] = e; work128[n1 * 2 + 1] = mb; ++n1; }
      int b = (ce + 63) >> 6;
      for (int mb = 0; mb < b; ++mb) { work64[n2 * 2] = e; work64[n2 * 2 + 1] = mb; ++n2; }
      woff[e] = o; o += ce;
    }
    for (int q = n1; q < WM128; ++q) { work128[q * 2] = -1; work128[q * 2 + 1] = 0; }
    for (int q = n2; q < WM64; ++q)  { work64[q * 2] = -1;  work64[q * 2 + 1] = 0; }
  }
}

// ---------------- up GEMMs (mag,freq) + activation ----------------
// BM=128, BN=64, BK=32, 256 thr (4 waves 2x2 of 64x32), double-buffered,
// LDS 33KB -> 4 blocks/CU. Chunk swizzle for 64B rows: c ^= (row>>1)&3.
__global__ __launch_bounds__(256, 4) void k_up(
    const unsigned short* __restrict__ xbf,
    const unsigned short* __restrict__ wmT,   // [e][HH][DD] bf16
    const unsigned short* __restrict__ wfT,   // [e][HH][DD] bf16
    const float* __restrict__ bphase,
    const int* __restrict__ cnt, const int* __restrict__ list_tok,
    const int* __restrict__ work, const int* __restrict__ woff,
    unsigned short* __restrict__ hid) {
  const int e = work[blockIdx.x * 2 + 0];
  if (e < 0) return;
  const int mt = work[blockIdx.x * 2 + 1];
  const int nt = blockIdx.y;
  const int ce = cnt[e];
  const int off = woff[e];
  __shared__ unsigned short As[2][128][32];   // 16 KB
  __shared__ unsigned short Bm[2][64][32];    // 8 KB
  __shared__ unsigned short Bf[2][64][32];    // 8 KB
  __shared__ int toks[128];
  const int tid = threadIdx.x;
  if (tid < 128) {
    int r = mt * 128 + tid;
    toks[tid] = list_tok[e * TT + (r < ce ? r : ce - 1)];
  }
  __syncthreads();
  const int w = tid >> 6, l = tid & 63;
  // A staging: 2 chunks/thread. chunk idx = p*256 + w*64 + l -> (row=idx>>2, c=l&3)
  size_t abase[2]; int aoff[2];
  #pragma unroll
  for (int p = 0; p < 2; ++p) {
    int row = p * 64 + w * 16 + (l >> 2);
    int g = (l & 3) ^ ((row >> 1) & 3);
    abase[p] = (size_t)toks[row] * DD + g * 8;
    aoff[p] = (p * 256 + w * 64 + l) * 8;
  }
  // B staging: 1 chunk/thread/matrix. chunk idx = w*64 + l -> (row=idx>>2, c=l&3)
  const int nrow = w * 16 + (l >> 2);
  const int gB = (l & 3) ^ ((nrow >> 1) & 3);
  const size_t bbase = ((size_t)e * HH + nt * 64 + nrow) * DD + gB * 8;
  const int boff = (w * 64 + l) * 8;

  const int wm = (w >> 1) * 64, wn = (w & 1) * 32;
  const int lr = l & 15, kg = l >> 4;
  const f32x4 zero = {0.f, 0.f, 0.f, 0.f};
  f32x4 accM[4][2], accF[4][2];
  #pragma unroll
  for (int a = 0; a < 4; ++a)
    #pragma unroll
    for (int b = 0; b < 2; ++b) { accM[a][b] = zero; accF[a][b] = zero; }

  auto stage = [&](int buf, int kt) {
    const int ko = kt * 32;
    unsigned short* As_b = &As[buf][0][0];
    unsigned short* Bm_b = &Bm[buf][0][0];
    unsigned short* Bf_b = &Bf[buf][0][0];
    #pragma unroll
    for (int p = 0; p < 2; ++p) gl_lds16(xbf + abase[p] + ko, As_b + aoff[p]);
    gl_lds16(wmT + bbase + ko, Bm_b + boff);
    gl_lds16(wfT + bbase + ko, Bf_b + boff);
  };

  stage(0, 0);
  __syncthreads();
  int buf = 0;
  for (int kt = 0; kt < DD / 32; ++kt) {
    if (kt + 1 < DD / 32) stage(buf ^ 1, kt + 1);
    bf16x8 av[4], bmv[2], bfv[2];
    #pragma unroll
    for (int fm = 0; fm < 4; ++fm) {
      int row = wm + fm * 16 + lr;
      int c = kg ^ ((row >> 1) & 3);
      av[fm] = *reinterpret_cast<const bf16x8*>(&As[buf][row][c * 8]);
    }
    #pragma unroll
    for (int fn = 0; fn < 2; ++fn) {
      int row = wn + fn * 16 + lr;
      int c = kg ^ ((row >> 1) & 3);
      bmv[fn] = *reinterpret_cast<const bf16x8*>(&Bm[buf][row][c * 8]);
      bfv[fn] = *reinterpret_cast<const bf16x8*>(&Bf[buf][row][c * 8]);
    }
    #pragma unroll
    for (int fm = 0; fm < 4; ++fm)
      #pragma unroll
      for (int fn = 0; fn < 2; ++fn) {
        accM[fm][fn] = __builtin_amdgcn_mfma_f32_16x16x32_bf16(av[fm], bmv[fn], accM[fm][fn], 0, 0, 0);
        accF[fm][fn] = __builtin_amdgcn_mfma_f32_16x16x32_bf16(av[fm], bfv[fn], accF[fm][fn], 0, 0, 0);
      }
    __syncthreads();
    buf ^= 1;
  }
  #pragma unroll
  for (int fn = 0; fn < 2; ++fn) {
    const int ng = nt * 64 + wn + fn * 16 + lr;
    const float ph = bphase[e * HH + ng] + 0.1f;
    #pragma unroll
    for (int fm = 0; fm < 4; ++fm) {
      #pragma unroll
      for (int jj = 0; jj < 4; ++jj) {
        int m = mt * 128 + wm + fm * 16 + kg * 4 + jj;
        if (m < ce) {
          float mv = accM[fm][fn][jj];
          float fv = accF[fm][fn][jj];
          float exn = __expf(-fabsf(fv));
          float sp = fmaxf(fv, 0.f) + __logf(1.f + exn);   // stable softplus
          float t2 = __expf(2.f * mv);
          float th = 1.f - 2.f / (t2 + 1.f);               // tanh
          float hv = th * __cosf(sp + ph);
          hid[(size_t)(off + m) * HH + ng] = f2bf(hv);
        }
      }
    }
  }
}

// ---------------- down GEMM ----------------
// BM=64, BN=64, BK=64, 256 thr (4 waves 2x2 of 32x32), LDS 32KB -> 4-5 blocks/CU,
// grid (WM64,16)=1280 blocks -> 5/CU.
__global__ __launch_bounds__(256, 4) void k_down(
    const unsigned short* __restrict__ hid,
    const unsigned short* __restrict__ wdT,   // [e][DD][HH] bf16
    const int* __restrict__ cnt,
    const int* __restrict__ work, const int* __restrict__ woff,
    unsigned short* __restrict__ op) {
  const int e = work[blockIdx.x * 2 + 0];
  if (e < 0) return;
  const int mt = work[blockIdx.x * 2 + 1];
  const int nt = blockIdx.y;
  const int ce = cnt[e];
  const int off = woff[e];
  __shared__ unsigned short As[2][64][64];   // 16 KB
  __shared__ unsigned short Bd[2][64][64];   // 16 KB
  const int tid = threadIdx.x;
  const int w = tid >> 6, l = tid & 63;
  // chunk idx = p*256 + w*64 + l -> (row = idx>>3, ch = l&7); 128B rows, swizzle ch ^= row&7
  size_t abase[2]; int aoff[2];
  size_t bbase[2]; int boff[2];
  #pragma unroll
  for (int p = 0; p < 2; ++p) {
    int row = p * 32 + w * 8 + (l >> 3);
    int ch = l & 7;
    int gr = mt * 64 + row; if (gr >= ce) gr = ce - 1;
    abase[p] = (size_t)(off + gr) * HH + (size_t)((ch ^ (row & 7)) * 8);
    aoff[p] = (p * 256 + w * 64 + l) * 8;
    bbase[p] = ((size_t)e * DD + nt * 64 + row) * HH + (size_t)((ch ^ (row & 7)) * 8);
    boff[p] = aoff[p];
  }
  const int wm = (w >> 1) * 32, wn = (w & 1) * 32;
  const int lr = l & 15, kg = l >> 4;
  const f32x4 zero = {0.f, 0.f, 0.f, 0.f};
  f32x4 acc[2][2];
  #pragma unroll
  for (int a = 0; a < 2; ++a)
    #pragma unroll
    for (int b = 0; b < 2; ++b) acc[a][b] = zero;

  auto stage = [&](int buf, int kt) {
    const int ko = kt * 64;
    unsigned short* As_b = &As[buf][0][0];
    unsigned short* Bd_b = &Bd[buf][0][0];
    #pragma unroll
    for (int p = 0; p < 2; ++p) {
      gl_lds16(hid + abase[p] + ko, As_b + aoff[p]);
      gl_lds16(wdT + bbase[p] + ko, Bd_b + boff[p]);
    }
  };

  stage(0, 0);
  __syncthreads();
  int buf = 0;
  for (int kt = 0; kt < HH / 64; ++kt) {
    if (kt + 1 < HH / 64) stage(buf ^ 1, kt + 1);
    #pragma unroll
    for (int ks = 0; ks < 2; ++ks) {
      bf16x8 av[2], bv[2];
      #pragma unroll
      for (int fm = 0; fm < 2; ++fm) {
        int row = wm + fm * 16 + lr;
        int c = (ks * 4 + kg) ^ (row & 7);
        av[fm] = *reinterpret_cast<const bf16x8*>(&As[buf][row][c * 8]);
      }
      #pragma unroll
      for (int fn = 0; fn < 2; ++fn) {
        int row = wn + fn * 16 + lr;
        int c = (ks * 4 + kg) ^ (row & 7);
        bv[fn] = *reinterpret_cast<const bf16x8*>(&Bd[buf][row][c * 8]);
      }
      #pragma unroll
      for (int fm = 0; fm < 2; ++fm)
        #pragma unroll
        for (int fn = 0; fn < 2; ++fn)
          acc[fm][fn] = __builtin_amdgcn_mfma_f32_16x16x32_bf16(av[fm], bv[fn], acc[fm][fn], 0, 0, 0);
    }
    __syncthreads();
    buf ^= 1;
  }
  #pragma unroll
  for (int fn = 0; fn < 2; ++fn) {
    const int ng = nt * 64 + wn + fn * 16 + lr;
    #pragma unroll
    for (int fm = 0; fm < 2; ++fm) {
      #pragma unroll
      for (int jj = 0; jj < 4; ++jj) {
        int m = mt * 64 + wm + fm * 16 + kg * 4 + jj;
        if (m < ce)
          op[(size_t)(off + m) * DD + ng] = f2bf(acc[fm][fn][jj]);
      }
    }
  }
}

// ---------------- combine + RMSNorm ----------------
__global__ __launch_bounds__(256) void k_norm(
    const unsigned short* __restrict__ op, const int* __restrict__ woff,
    const int* __restrict__ rec, const float* __restrict__ wrec,
    const float* __restrict__ nw, float* __restrict__ out) {
  const int t = blockIdx.x;
  const int tid = threadIdx.x;
  __shared__ float red[4];
  const int e1 = rec[t * 4 + 0], p1 = rec[t * 4 + 1];
  const int e2 = rec[t * 4 + 2], p2 = rec[t * 4 + 3];
  const float w1 = wrec[t * 2 + 0], w2 = wrec[t * 2 + 1];
  const unsigned short* pa = op + (size_t)(woff[e1] + p1) * DD;
  const unsigned short* pb = op + (size_t)(woff[e2] + p2) * DD;
  float v[4]; float ss = 0.f;
  #pragma unroll
  for (int q = 0; q < 4; ++q) {
    int i = q * 256 + tid;
    v[q] = w1 * bf2f(pa[i]) + w2 * bf2f(pb[i]);
    ss += v[q] * v[q];
  }
  #pragma unroll
  for (int o = 32; o > 0; o >>= 1) ss += __shfl_xor(ss, o);
  if ((tid & 63) == 0) red[tid >> 6] = ss;
  __syncthreads();
  const float tot = red[0] + red[1] + red[2] + red[3];
  const float scl = rsqrtf(tot * (1.f / DD) + 1e-6f);
  #pragma unroll
  for (int q = 0; q < 4; ++q) {
    int i = q * 256 + tid;
    out[(size_t)t * DD + i] = v[q] * scl * nw[i];
  }
}

extern "C" void kernel_launch(void* const* d_in, const int* in_sizes, int n_in,
                              void* d_out, int out_size, void* d_ws, size_t ws_size,
                              hipStream_t stream) {
  const float* x      = (const float*)d_in[0];
  const float* rw     = (const float*)d_in[1];
  const float* rb     = (const float*)d_in[2];
  const float* bmag   = (const float*)d_in[3];
  const float* bfreq  = (const float*)d_in[4];
  const float* bphase = (const float*)d_in[5];
  const float* bdown  = (const float*)d_in[6];
  const float* nw     = (const float*)d_in[7];
  float* out = (float*)d_out;
  char* ws = (char*)d_ws;
  const size_t MB = 1024 * 1024;
  int*   cnt    = (int*)(ws + 0);          // 16 int
  int*   work1  = (int*)(ws + 128);        // WM128*2 int
  int*   work2  = (int*)(ws + 1024);       // WM64*2 int
  int*   woff   = (int*)(ws + 2048);       // 16 int
  int*   list   = (int*)(ws + 4096);       // 16*2048 int
  int*   rec    = (int*)(ws + 139264);     // 2048*4 int
  float* wrec   = (float*)(ws + 172032);   // 2048*2 f32
  unsigned short* xbf = (unsigned short*)(ws + 1 * MB);    // 4 MB
  unsigned short* hid = (unsigned short*)(ws + 5 * MB);    // 16 MB
  unsigned short* op  = (unsigned short*)(ws + 21 * MB);   // 8 MB
  unsigned short* wmT = (unsigned short*)(ws + 32 * MB);   // 64 MB (reused by wdT)
  unsigned short* wfT = (unsigned short*)(ws + 96 * MB);   // 64 MB
  unsigned short* wdT = wmT;                               // alias: used after k_up

  hipMemsetAsync(cnt, 0, 64, stream);
  k_cvt_x<<<1024, 256, 0, stream>>>(x, xbf);
  k_router<<<TT, 256, 0, stream>>>(x, rw, rb, cnt, list, rec, wrec);
  k_sched<<<1, 64, 0, stream>>>(cnt, work1, work2, woff);
  // mag + freq transposes in one launch (z = 32: 16 experts x 2 matrices)
  k_trans<<<dim3(HH / 64, DD / 64, 32), 256, 0, stream>>>(bmag, bfreq, wmT, wfT, DD, HH);
  k_up<<<dim3(WM128, HH / 64), 256, 0, stream>>>(xbf, wmT, wfT, bphase, cnt, list, work1, woff, hid);
  k_trans<<<dim3(DD / 64, HH / 64, 16), 256, 0, stream>>>(bdown, bdown, wdT, wdT, HH, DD);
  k_down<<<dim3(WM64, DD / 64), 256, 0, stream>>>(hid, wdT, cnt, work2, woff, op);
  k_norm<<<TT, 256, 0, stream>>>(op, woff, rec, wrec, nw, out);
}